// Round 3
// baseline (110.215 us; speedup 1.0000x reference)
//
#include <hip/hip_runtime.h>
#include <cstdint>
#include <cstddef>

// ============================================================================
// ProposalTargetLayer (MSDN / Faster-RCNN), gfx950. Round 3.
// Pipeline: memset(hist) -> k_prep -> k_select -> k_final
//  - k_prep: per-roi fg mask WITHOUT divide (exact f32 fma threshold test),
//    PRNG keys, vb value-bits, global histogram atomics. No argmax here.
//  - k_select: histogram scan -> threshold bin -> one filtered pass over vb
//    -> exact rank of ~K+6 candidates (64-bit key keeps XLA tie-break).
//  - k_final: argmax for the 4096 selected rois only, using the EXACT
//    reference op order (f32 correctly-rounded div, strict > first-win),
//    then bbox transform + outputs.
// All discrete decisions bit-exact vs the numpy reference:
//  * fg test: round(inter/denom) >= 0.5  <=>  ratio >= 0.5-2^-26
//    <=> fmaf(-0.5,denom,inter) >= (-2^-26)*denom  (fma exact by Sterbenz in
//    the cancellation zone ratio in [0.25,1]; exact exponent-shift RHS).
//  * bg = !fg (iou >= 0 always, BG_LO = 0).
//  * top_k stable tie-break via (valbits<<32)|(~idx) exact ranking.
// ============================================================================

#define THREEFRY_PARTITIONABLE 1

constexpr int kB = 16;
constexpr int kN = 12000;
constexpr int kG = 128;
constexpr int kM = kN + kG;   // 12128
constexpr int kM4 = kM / 4;   // 3032 (exact)
constexpr int kR = 256;
constexpr int kFgQuota = 64;
constexpr unsigned kSeedHi = 0u;
constexpr unsigned kSeedLo = 42u;   // jax.random.key(42)

__device__ __forceinline__ int imin(int a, int b) { return a < b ? a : b; }
__device__ __forceinline__ int imax(int a, int b) { return a > b ? a : b; }

__device__ __forceinline__ unsigned rotl32(unsigned v, int d) {
  return (v << d) | (v >> (32 - d));
}

// Threefry-2x32, 20 rounds, exactly as in jax/_src/prng.py.
__device__ __forceinline__ void tf2x32(unsigned k0, unsigned k1,
                                       unsigned x0, unsigned x1,
                                       unsigned& o0, unsigned& o1) {
  const unsigned k2 = k0 ^ k1 ^ 0x1BD11BDAu;
  x0 += k0; x1 += k1;
#define TF_R(d) x0 += x1; x1 = rotl32(x1, d); x1 ^= x0;
  TF_R(13) TF_R(15) TF_R(26) TF_R(6)
  x0 += k1; x1 += k2 + 1u;
  TF_R(17) TF_R(29) TF_R(16) TF_R(24)
  x0 += k2; x1 += k0 + 2u;
  TF_R(13) TF_R(15) TF_R(26) TF_R(6)
  x0 += k0; x1 += k1 + 3u;
  TF_R(17) TF_R(29) TF_R(16) TF_R(24)
  x0 += k1; x1 += k2 + 4u;
  TF_R(13) TF_R(15) TF_R(26) TF_R(6)
  x0 += k2; x1 += k0 + 5u;
#undef TF_R
  o0 = x0; o1 = x1;
}

__device__ __forceinline__ void derive_key(int which, unsigned& ka, unsigned& kb) {
#if THREEFRY_PARTITIONABLE
  tf2x32(kSeedHi, kSeedLo, 0u, (unsigned)which, ka, kb);
#else
  unsigned a0, a1, b0, b1;
  tf2x32(kSeedHi, kSeedLo, 0u, 2u, a0, a1);
  tf2x32(kSeedHi, kSeedLo, 1u, 3u, b0, b1);
  if (which == 0) { ka = a0; kb = b0; } else { ka = a1; kb = b1; }
#endif
}

__device__ __forceinline__ float bits_to_uniform(unsigned bits) {
  return __uint_as_float((bits >> 9) | 0x3f800000u) - 1.0f;
}

__device__ __forceinline__ float jax_uniform(unsigned ka, unsigned kb, unsigned i) {
#if THREEFRY_PARTITIONABLE
  unsigned o0, o1;
  tf2x32(ka, kb, 0u, i, o0, o1);
  return bits_to_uniform(o0 ^ o1);
#else
  const unsigned H = (unsigned)(kB * kM) / 2u;
  unsigned o0, o1;
  if (i < H) { tf2x32(ka, kb, i, i + H, o0, o1); return bits_to_uniform(o0); }
  else       { tf2x32(ka, kb, i - H, i, o0, o1); return bits_to_uniform(o1); }
#endif
}

// in-mask bin: monotone in value. v in [0x40000000, 0x40400000] (2.0..3.0).
__device__ __forceinline__ unsigned mask_bin(unsigned v) {
  unsigned bn = (v - 0x40000000u) >> 11;
  return bn > 2047u ? 2047u : bn;   // exact-3.0 corner merges into top bin
}

// ---------------------------------------------------------------------------
// Kernel A: per (b, m): fg mask (no divide), PRNG, vb value-bits, global
// histogram atomics. No argmax (deferred to k_final for selected rois only).
// ---------------------------------------------------------------------------
__global__ __launch_bounds__(256) void k_prep(const float* __restrict__ all_rois,
                                              const float* __restrict__ gt_boxes,
                                              unsigned* __restrict__ vb,
                                              int* __restrict__ hist) {
  __shared__ float4 sg[kG];
  __shared__ float sga[kG];
  const int b = blockIdx.y;
  const int m = blockIdx.x * 256 + threadIdx.x;
  if (threadIdx.x < kG) {
    const float* gp = gt_boxes + ((size_t)b * kG + threadIdx.x) * 5;
    const float x0 = gp[0], y0 = gp[1], x1 = gp[2], y1 = gp[3];
    sg[threadIdx.x] = make_float4(x0, y0, x1, y1);
    sga[threadIdx.x] = ((x1 - x0) + 1.0f) * ((y1 - y0) + 1.0f);
  }
  __syncthreads();
  if (m >= kM) return;

  float bx0, by0, bx1, by1;
  if (m < kN) {
    const float* rp = all_rois + ((size_t)b * kN + m) * 5;
    bx0 = rp[1]; by0 = rp[2]; bx1 = rp[3]; by1 = rp[4];
  } else {
    const float4 g4 = sg[m - kN];
    bx0 = g4.x; by0 = g4.y; bx1 = g4.z; by1 = g4.w;
  }
  const float areab = ((bx1 - bx0) + 1.0f) * ((by1 - by0) + 1.0f);

  // fg <=> exists g: round(inter/denom) >= 0.5 <=> ratio >= 0.5-2^-26.
  // Exact pure-f32 test (see header). No divide, no argmax.
  bool fg = false;
#pragma unroll 8
  for (int g = 0; g < kG; ++g) {
    const float4 g4 = sg[g];
    const float xx0 = fmaxf(bx0, g4.x);
    const float yy0 = fmaxf(by0, g4.y);
    const float xx1 = fminf(bx1, g4.z);
    const float yy1 = fminf(by1, g4.w);
    const float iw = fmaxf((xx1 - xx0) + 1.0f, 0.0f);
    const float ih = fmaxf((yy1 - yy0) + 1.0f, 0.0f);
    const float inter = iw * ih;
    const float denom = (areab + sga[g]) - inter;   // ref op order
    fg = fg || (__builtin_fmaf(-0.5f, denom, inter) >= (-0x1p-26f) * denom);
  }

  unsigned k1a, k1b, k2a, k2b;
  derive_key(0, k1a, k1b);
  derive_key(1, k2a, k2b);
  const unsigned i = (unsigned)(b * kM + m);
  const float r1 = jax_uniform(k1a, k1b, i);
  const float r2 = jax_uniform(k2a, k2b, i);
  const float v1 = fg ? (r1 + 2.0f) : r1;
  const float v2 = fg ? r2 : (r2 + 2.0f);          // bg = !fg
  const unsigned u1 = __float_as_uint(v1);
  const unsigned u2 = __float_as_uint(v2);
  vb[(size_t)b * kM + m] = u1;
  vb[(size_t)(kB + b) * kM + m] = u2;
  if (fg) atomicAdd(&hist[(size_t)b * 2048 + mask_bin(u1)], 1);
  else    atomicAdd(&hist[(size_t)(kB + b) * 2048 + mask_bin(u2)], 1);
}

__device__ __forceinline__ int block_reduce_sum(int v, int* s_red, int tid) {
#pragma unroll
  for (int off = 32; off > 0; off >>= 1) v += __shfl_down(v, off, 64);
  __syncthreads();
  if ((tid & 63) == 0) s_red[tid >> 6] = v;
  __syncthreads();
  return s_red[0] + s_red[1] + s_red[2] + s_red[3];
}

// ---------------------------------------------------------------------------
// Kernel B: one block per (which, b). Histogram scan -> threshold bin ->
// single filtered pass over vb -> exact rank of candidates.
// ---------------------------------------------------------------------------
__global__ __launch_bounds__(256) void k_select(const unsigned* __restrict__ vb,
                                                const int* __restrict__ hist,
                                                int* __restrict__ topidx,
                                                int* __restrict__ nin) {
  __shared__ int s_hist[2048];                  // 8 KB
  __shared__ unsigned long long s_cand[1024];   // 8 KB
  __shared__ int s_scan[256];
  __shared__ int s_red[4];
  __shared__ unsigned long long s_wmax[4];
  __shared__ int s_tbin, s_cnt;

  const int which = blockIdx.x;
  const int b = blockIdx.y;
  const int tid = threadIdx.x;
  const unsigned* src = vb + (size_t)(which * kB + b) * kM;
  const int* hrow = hist + (size_t)(which * kB + b) * 2048;
  int* dst = topidx + (size_t)(which * kB + b) * kR;

  for (int i = tid; i < 2048; i += 256) s_hist[i] = hrow[i];
  if (tid == 0) s_cnt = 0;
  __syncthreads();

  // descending 8-bin chunk per thread
  const int base = 2048 - 8 * (tid + 1);
  int s = 0;
#pragma unroll
  for (int j = 0; j < 8; ++j) s += s_hist[base + j];
  const int n_in = block_reduce_sum(s, s_red, tid);   // sum of all bins
  if (tid == 0) nin[which * kB + b] = n_in;
  const int quota = (which == 0) ? kFgQuota : kR;
  const int K = imin(n_in, quota);

  if (K == 0) {
    if (which == 0) return;  // fgc==0 -> fg slots never read
    // bg degenerate: reference takes top of UNMASKED r2 -> plain argmax.
    unsigned long long best = 0ull;
    for (int m = tid; m < kM; m += 256) {
      const unsigned long long key =
          ((unsigned long long)src[m] << 32) | (unsigned)(0xFFFFFFFFu - (unsigned)m);
      if (key > best) best = key;
    }
#pragma unroll
    for (int off = 32; off > 0; off >>= 1) {
      const unsigned long long o = __shfl_down(best, off, 64);
      if (o > best) best = o;
    }
    if ((tid & 63) == 0) s_wmax[tid >> 6] = best;
    __syncthreads();
    if (tid == 0) {
      for (int w = 1; w < 4; ++w) if (s_wmax[w] > best) best = s_wmax[w];
      dst[0] = (int)(0xFFFFFFFFu - (unsigned)(best & 0xFFFFFFFFull));
    }
    return;
  }

  // inclusive scan over descending chunk sums -> threshold bin
  s_scan[tid] = s;
  __syncthreads();
  for (int off = 1; off < 256; off <<= 1) {
    const int add = (tid >= off) ? s_scan[tid - off] : 0;
    __syncthreads();
    s_scan[tid] += add;
    __syncthreads();
  }
  const int above = s_scan[tid] - s;  // count in bins above my chunk
  int cum = above;
  for (int j = 7; j >= 0; --j) {      // unique crossing bin: cum < K <= cum+c
    const int c = s_hist[base + j];
    if (cum < K && cum + c >= K) s_tbin = base + j;
    cum += c;
  }
  __syncthreads();
  const unsigned tbin = (unsigned)s_tbin;

  // one filtered coalesced pass over vb: collect candidates (~K + lambda)
  const uint4* src4 = (const uint4*)src;
  for (int i = tid; i < kM4; i += 256) {
    const uint4 u = src4[i];
#define CAND(x, j)                                                         \
    if ((x) >= 0x40000000u && mask_bin(x) >= tbin) {                       \
      const int p = atomicAdd(&s_cnt, 1);                                  \
      if (p < 1024)                                                        \
        s_cand[p] = ((unsigned long long)(x) << 32) |                      \
                    (unsigned)(0xFFFFFFFFu - (unsigned)(4 * i + (j)));     \
    }
    CAND(u.x, 0) CAND(u.y, 1) CAND(u.z, 2) CAND(u.w, 3)
#undef CAND
  }
  __syncthreads();
  const int Nc = imin(s_cnt, 1024);

  // exact rank among candidates (keys pairwise distinct)
  for (int j = tid; j < Nc; j += 256) {
    const unsigned long long key = s_cand[j];
    int rank = 0;
    for (int i = 0; i < Nc; ++i) rank += (s_cand[i] > key) ? 1 : 0;
    if (rank < K)
      dst[rank] = (int)(0xFFFFFFFFu - (unsigned)(key & 0xFFFFFFFFull));
  }
}

// ---------------------------------------------------------------------------
// Kernel C: per selected roi: reference-exact argmax (f32 div, strict >,
// first-win) over 128 gt, then bbox transform + outputs.
// ---------------------------------------------------------------------------
__global__ __launch_bounds__(256) void k_final(const float* __restrict__ all_rois,
                                               const float* __restrict__ gt_boxes,
                                               const int* __restrict__ topidx,
                                               const int* __restrict__ nin,
                                               float* __restrict__ out) {
  __shared__ float4 sg[kG];
  __shared__ float sga[kG];
  __shared__ float slab[kG];
  const int b = blockIdx.x;
  const int pos = threadIdx.x;
  if (threadIdx.x < kG) {
    const float* gp = gt_boxes + ((size_t)b * kG + threadIdx.x) * 5;
    const float x0 = gp[0], y0 = gp[1], x1 = gp[2], y1 = gp[3];
    sg[threadIdx.x] = make_float4(x0, y0, x1, y1);
    sga[threadIdx.x] = ((x1 - x0) + 1.0f) * ((y1 - y0) + 1.0f);
    slab[threadIdx.x] = gp[4];
  }
  __syncthreads();

  const int fgnum = nin[b];
  const int bgnum = nin[kB + b];
  const int fgc = imin(fgnum, kFgQuota);
  const int bgav = imin(imax(bgnum, 1), kR);
  const int* fgtop = topidx + (size_t)b * kR;
  const int* bgtop = topidx + (size_t)(kB + b) * kR;

  const bool isfg = pos < fgc;
  int keep;
  if (isfg) keep = fgtop[imin(pos, imax(fgc - 1, 0))];
  else      keep = bgtop[(pos - fgc) % bgav];

  float bx0, by0, bx1, by1;
  if (keep < kN) {
    const float* rp = all_rois + ((size_t)b * kN + keep) * 5;
    bx0 = rp[1]; by0 = rp[2]; bx1 = rp[3]; by1 = rp[4];
  } else {
    const float4 g4 = sg[keep - kN];
    bx0 = g4.x; by0 = g4.y; bx1 = g4.z; by1 = g4.w;
  }
  const float areab = ((bx1 - bx0) + 1.0f) * ((by1 - by0) + 1.0f);

  // reference-exact argmax (first strict max over rounded quotients)
  float best = -1.0f;
  int a = 0;
  for (int g = 0; g < kG; ++g) {
    const float4 g4 = sg[g];
    const float xx0 = fmaxf(bx0, g4.x);
    const float yy0 = fmaxf(by0, g4.y);
    const float xx1 = fminf(bx1, g4.z);
    const float yy1 = fminf(by1, g4.w);
    const float iw = fmaxf((xx1 - xx0) + 1.0f, 0.0f);
    const float ih = fmaxf((yy1 - yy0) + 1.0f, 0.0f);
    const float inter = iw * ih;
    const float iou = inter / ((areab + sga[g]) - inter);
    if (iou > best) { best = iou; a = g; }
  }

  const float4 gt4 = sg[a];
  const float gx0 = gt4.x, gy0 = gt4.y, gx1 = gt4.z, gy1 = gt4.w;
  const float lab = isfg ? slab[a] : 0.0f;
  const float fg4 = (lab > 0.0f) ? 1.0f : 0.0f;

  const float ew = (bx1 - bx0) + 1.0f;
  const float eh = (by1 - by0) + 1.0f;
  const float ecx = bx0 + 0.5f * ew;
  const float ecy = by0 + 0.5f * eh;
  const float gw = (gx1 - gx0) + 1.0f;
  const float gh = (gy1 - gy0) + 1.0f;
  const float gcx = gx0 + 0.5f * gw;
  const float gcy = gy0 + 0.5f * gh;
  const float t0 = ((gcx - ecx) / ew) / 0.1f;
  const float t1 = ((gcy - ecy) / eh) / 0.1f;
  const float t2 = logf(gw / ew) / 0.2f;
  const float t3 = logf(gh / eh) / 0.2f;

  float* o_rois = out;                                   // [B,R,5]
  float* o_lab  = out + (size_t)kB * kR * 5;             // [B,R]
  float* o_tgt  = o_lab + (size_t)kB * kR;               // [B,R,4]
  float* o_iw   = o_tgt + (size_t)kB * kR * 4;           // [B,R,4]
  float* o_ow   = o_iw  + (size_t)kB * kR * 4;           // [B,R,4]
  const size_t p = (size_t)b * kR + pos;
  o_rois[p * 5 + 0] = (float)b;
  o_rois[p * 5 + 1] = bx0;
  o_rois[p * 5 + 2] = by0;
  o_rois[p * 5 + 3] = bx1;
  o_rois[p * 5 + 4] = by1;
  o_lab[p] = lab;
  o_tgt[p * 4 + 0] = t0 * fg4;
  o_tgt[p * 4 + 1] = t1 * fg4;
  o_tgt[p * 4 + 2] = t2 * fg4;
  o_tgt[p * 4 + 3] = t3 * fg4;
  o_iw[p * 4 + 0] = fg4; o_iw[p * 4 + 1] = fg4;
  o_iw[p * 4 + 2] = fg4; o_iw[p * 4 + 3] = fg4;
  o_ow[p * 4 + 0] = fg4; o_ow[p * 4 + 1] = fg4;
  o_ow[p * 4 + 2] = fg4; o_ow[p * 4 + 3] = fg4;
}

extern "C" void kernel_launch(void* const* d_in, const int* in_sizes, int n_in_args,
                              void* d_out, int out_size, void* d_ws, size_t ws_size,
                              hipStream_t stream) {
  (void)in_sizes; (void)n_in_args; (void)out_size; (void)ws_size;
  const float* all_rois = (const float*)d_in[0];  // [16,12000,5] fp32
  const float* gt_boxes = (const float*)d_in[1];  // [16,128,5] fp32
  float* out = (float*)d_out;

  char* ws = (char*)d_ws;
  unsigned* vb = (unsigned*)ws;                       // 2*kB*kM u32 = 1552384 B
  int* hist    = (int*)(ws + 1572864);                // 2*kB*2048 int = 256 KB
  int* topidx  = (int*)(ws + 1572864 + 262144);       // 2*kB*kR int = 32 KB
  int* nin     = (int*)(ws + 1572864 + 262144 + 32768); // 32 int

  hipMemsetAsync(hist, 0, (size_t)2 * kB * 2048 * sizeof(int), stream);
  dim3 gA((kM + 255) / 256, kB);
  k_prep<<<gA, 256, 0, stream>>>(all_rois, gt_boxes, vb, hist);
  dim3 gB(2, kB);
  k_select<<<gB, 256, 0, stream>>>(vb, hist, topidx, nin);
  k_final<<<kB, kR, 0, stream>>>(all_rois, gt_boxes, topidx, nin, out);
}